// Round 10
// baseline (862.439 us; speedup 1.0000x reference)
//
#include <hip/hip_runtime.h>

#define VSZ 32000
#define DSZ 256
#define BSZ 32
#define MSZ 1024
#define PSZ 1025
#define VD  (VSZ * DSZ)
#define XSTRIDE 260   // 256 + 4 pad: 4 b-addresses land in banks 0/4/8/12 -> conflict-free

// Workspace layout (float offsets)
#define OFF_U     32768                 // after int pos[M*B]
#define OFF_U0    40960
#define OFF_PP    49152                 // [B][PSZ] = 32800
#define OFF_GIH   81952                 // [1536][B] = 49152
#define OFF_SC    131104                // [M][B] = 32768
#define OFF_PMAX  163872                // [128][B]
#define OFF_PSUM  167968                // [128][B]
#define OFF_PROJ  172064                // [B][V] = 1024000

// Output layout (floats): prob_lg [B,M] | p_vocab [B,V] | hidden [1,B,D]
#define OUT_PV  (BSZ * MSZ)
#define OUT_HID (OUT_PV + BSZ * VSZ)

// ---------------------------------------------------------------------------
// streamAcc: lane = (vq = lane&15, bq = lane>>4); wave = 16 rows x 4 b;
// 8 waves (512 thr) cover 32 b on the same 16*ROWS rows. Each lane owns
// ROWS rows x ONE b. x-reads: 4 distinct LDS addrs/inst (stride-pad -> no
// bank conflict), 1024B useful per inst (vs 16B broadcast in R9 scheme).
// x double-buffered in registers; W prefetched 1 step (8 cols) ahead.
template <int ROWS>
__device__ __forceinline__ void streamAcc(
    const float* __restrict__ W, int wstride,
    const float* __restrict__ xS,   // [32][XSTRIDE]
    float* __restrict__ acc,        // [ROWS]
    int rbeg, int rend, int t)
{
    const int lane = t & 63;
    const int bq = lane >> 4, vq = lane & 15;
    const int b = (t >> 6) * 4 + bq;
    const float* xp = xS + (size_t)b * XSTRIDE;
    const float* wp[ROWS];
#pragma unroll
    for (int k = 0; k < ROWS; ++k) {
        int r = rbeg + vq + 16 * k;
        wp[k] = W + (size_t)((r < rend) ? r : rbeg) * wstride;
    }
    float4 ca[ROWS][2], na[ROWS][2], xa[2], xb[2];
#pragma unroll
    for (int k = 0; k < ROWS; ++k) {
        ca[k][0] = *(const float4*)(wp[k]);
        ca[k][1] = *(const float4*)(wp[k] + 4);
    }
    xa[0] = *(const float4*)(xp);
    xa[1] = *(const float4*)(xp + 4);
    constexpr int NS = DSZ / 8;     // 32 steps of 8 cols
    for (int s = 0; s < NS; ++s) {
        if (s + 1 < NS) {
#pragma unroll
            for (int k = 0; k < ROWS; ++k) {
                na[k][0] = *(const float4*)(wp[k] + (s + 1) * 8);
                na[k][1] = *(const float4*)(wp[k] + (s + 1) * 8 + 4);
            }
            xb[0] = *(const float4*)(xp + (s + 1) * 8);
            xb[1] = *(const float4*)(xp + (s + 1) * 8 + 4);
        }
#pragma unroll
        for (int k = 0; k < ROWS; ++k) {
            acc[k] += ca[k][0].x * xa[0].x + ca[k][0].y * xa[0].y +
                      ca[k][0].z * xa[0].z + ca[k][0].w * xa[0].w +
                      ca[k][1].x * xa[1].x + ca[k][1].y * xa[1].y +
                      ca[k][1].z * xa[1].z + ca[k][1].w * xa[1].w;
        }
#pragma unroll
        for (int k = 0; k < ROWS; ++k) { ca[k][0] = na[k][0]; ca[k][1] = na[k][1]; }
        xa[0] = xb[0]; xa[1] = xb[1];
    }
}

template <int ROWS>
__device__ __forceinline__ void writeV(
    const float* acc, float* __restrict__ dest, const float* __restrict__ bias,
    size_t drow, size_t dcol, int rbeg, int rend, int t)
{
    const int lane = t & 63;
    const int bq = lane >> 4, vq = lane & 15;
    const int b = (t >> 6) * 4 + bq;
#pragma unroll
    for (int k = 0; k < ROWS; ++k) {
        int r = rbeg + vq + 16 * k;
        if (r < rend)
            dest[(size_t)r * drow + (size_t)b * dcol] = acc[k] + (bias ? bias[r] : 0.f);
    }
}

// stage contiguous [32][256] source into padded xS
__device__ __forceinline__ void stage256(const float* __restrict__ src,
                                         float* __restrict__ xS, int t) {
    for (int i = t; i < BSZ * 64; i += 512) {
        int b = i >> 6, c4 = i & 63;
        *(float4*)&xS[(size_t)b * XSTRIDE + c4 * 4] = ((const float4*)src)[i];
    }
}

// ---------------------------------------------------------------------------
// K1: positions (blocks 0..31, 2 m/thread) || GRU matvec (blocks 32..43)
__global__ __launch_bounds__(512) void k_posgru(
    const int* __restrict__ story, const int* __restrict__ encq,
    const float* __restrict__ lasth, const float* __restrict__ C0,
    const float* __restrict__ gwih, const float* __restrict__ gwhh,
    int* __restrict__ pos, float* __restrict__ gih)
{
    __shared__ float xS[BSZ * XSTRIDE];
    int gid = blockIdx.x, t = threadIdx.x;
    int lane = t & 63, wid = t >> 6;
    if (gid < 32) {
        int* wtot = (int*)xS;
        int b = gid, m0 = t * 2;
        int f0 = story[(size_t)(m0 * BSZ + b) * 4] != 0;
        int f1 = story[(size_t)((m0 + 1) * BSZ + b) * 4] != 0;
        int p2 = f0 + f1;
        int x = p2;
        for (int o = 1; o < 64; o <<= 1) {
            int v = __shfl_up(x, o, 64);
            if (lane >= o) x += v;
        }
        if (lane == 63) wtot[wid] = x;
        __syncthreads();
        int wo = 0;
        for (int i = 0; i < wid; ++i) wo += wtot[i];
        int base = wo + x - p2;
        pos[m0 * BSZ + b] = f0 ? base + f0 : 0;
        pos[(m0 + 1) * BSZ + b] = f1 ? base + p2 : 0;
    } else {
        int k = gid - 32;              // 0..11
        bool isX = (k < 6);
        for (int i = t; i < BSZ * 64; i += 512) {
            int b = i >> 6, c4 = i & 63;
            float4 v = isX ? ((const float4*)(C0 + (size_t)encq[b] * DSZ))[c4]
                           : ((const float4*)(lasth + (size_t)b * DSZ))[c4];
            *(float4*)&xS[(size_t)b * XSTRIDE + c4 * 4] = v;
        }
        __syncthreads();
        int kr = isX ? k : k - 6;
        const float* W = isX ? gwih : gwhh;
        float* dest = gih + (isX ? 0 : 768 * BSZ);
        float acc[8] = {};
        streamAcc<8>(W, DSZ, xS, acc, kr * 128, kr * 128 + 128, t);
        writeV<8>(acc, dest, nullptr, BSZ, 1, kr * 128, kr * 128 + 128, t);
    }
}

// ---------------------------------------------------------------------------
// K2: GRU finalize. 32 x 256, idx = b + 32*d (coalesced gih reads).
__global__ void k_grufin(const float* __restrict__ gih,
                         const float* __restrict__ gbih, const float* __restrict__ gbhh,
                         const float* __restrict__ lasth,
                         float* __restrict__ u, float* __restrict__ u0,
                         float* __restrict__ hid)
{
    int idx = blockIdx.x * 256 + threadIdx.x;
    int b = idx & 31, d = idx >> 5;
    float gi0 = gih[(size_t)(0 * DSZ + d) * BSZ + b] + gbih[0 * DSZ + d];
    float gi1 = gih[(size_t)(1 * DSZ + d) * BSZ + b] + gbih[1 * DSZ + d];
    float gi2 = gih[(size_t)(2 * DSZ + d) * BSZ + b] + gbih[2 * DSZ + d];
    float gh0 = gih[(size_t)(3 * DSZ + d) * BSZ + b] + gbhh[0 * DSZ + d];
    float gh1 = gih[(size_t)(4 * DSZ + d) * BSZ + b] + gbhh[1 * DSZ + d];
    float gh2 = gih[(size_t)(5 * DSZ + d) * BSZ + b] + gbhh[2 * DSZ + d];
    float r = 1.f / (1.f + __expf(-(gi0 + gh0)));
    float z = 1.f / (1.f + __expf(-(gi1 + gh1)));
    float n = tanhf(gi2 + r * gh2);
    float h = lasth[(size_t)b * DSZ + d];
    float hn = (1.f - z) * n + z * h;
    int o = b * DSZ + d;
    u[o] = hn; u0[o] = hn; hid[o] = hn;
}

// ---------------------------------------------------------------------------
// K3/K7: proj (blocks < nproj, 128 rows each) + posproj tail blocks.
__global__ __launch_bounds__(512) void k_proj(
    const float* __restrict__ Ct, const float* __restrict__ postab,
    const float* __restrict__ u, float* __restrict__ proj,
    float* __restrict__ pp, int nproj)
{
    __shared__ float xS[BSZ * XSTRIDE];
    int gid = blockIdx.x, t = threadIdx.x;
    stage256(u, xS, t);
    __syncthreads();
    float acc[8] = {};
    if (gid < nproj) {
        int rb = gid * 128;
        streamAcc<8>(Ct, DSZ, xS, acc, rb, rb + 128, t);
        writeV<8>(acc, proj, nullptr, 1, VSZ, rb, rb + 128, t);
    } else {
        int rb = (gid - nproj) * 128;
        int re = min(rb + 128, PSZ);
        streamAcc<8>(postab, DSZ, xS, acc, rb, re, t);
        writeV<8>(acc, pp, nullptr, 1, PSZ, rb, re, t);
    }
}

// ---------------------------------------------------------------------------
// K4: scores (+ per-block softmax stats for hop<2; logits to out at hop 2).
__global__ void k_scores(const int* __restrict__ story, const int* __restrict__ pos,
                         const float* __restrict__ proj, const float* __restrict__ pp,
                         float* __restrict__ sc, float* __restrict__ pmax,
                         float* __restrict__ psum, float* __restrict__ outlg, int hop)
{
    __shared__ float red[256];
    int gid = blockIdx.x, t = threadIdx.x;
    int idx = gid * 256 + t;
    int b = idx & 31, m = idx >> 5;
    int4 st = *(const int4*)&story[(size_t)idx * 4];
    const float* pb = proj + (size_t)b * VSZ;
    float s = pb[st.x] + pb[st.y] + pb[st.z] + pb[st.w];
    if (hop == 0) s += pp[(size_t)b * PSZ + pos[idx]];
    if (hop == 2) { outlg[b * MSZ + m] = s; return; }
    sc[idx] = s;
    red[t] = s;
    __syncthreads();
    if (t < 32) {
        float mx = red[t];
#pragma unroll
        for (int k = 1; k < 8; ++k) mx = fmaxf(mx, red[k * 32 + t]);
        float sm = 0.f;
#pragma unroll
        for (int k = 0; k < 8; ++k) sm += __expf(red[k * 32 + t] - mx);
        pmax[gid * 32 + t] = mx;
        psum[gid * 32 + t] = sm;
    }
}

// ---------------------------------------------------------------------------
// K5: gather-PV. 512 blocks = (16 mc x 32 b), 256 thr = 4 m-groups x 64 d-lanes.
__global__ __launch_bounds__(256) void k_okpv(
    const int* __restrict__ story, const float* __restrict__ sc,
    const float* __restrict__ pmax, const float* __restrict__ psum,
    const float* __restrict__ Ct, float* __restrict__ u)
{
    int b = blockIdx.x & 31, mc = blockIdx.x >> 5;
    int t = threadIdx.x;
    __shared__ float red[256];
    __shared__ float pl[64];
    __shared__ float4 pt[4][64];
    red[t] = (t < 128) ? pmax[t * 32 + b] : -3.4e38f;
    __syncthreads();
    for (int o = 128; o >= 1; o >>= 1) {
        if (t < o) red[t] = fmaxf(red[t], red[t + o]);
        __syncthreads();
    }
    float M = red[0];
    __syncthreads();
    red[t] = (t < 128) ? psum[t * 32 + b] * __expf(pmax[t * 32 + b] - M) : 0.f;
    __syncthreads();
    for (int o = 128; o >= 1; o >>= 1) {
        if (t < o) red[t] += red[t + o];
        __syncthreads();
    }
    float S = red[0];
    __syncthreads();
    if (t < 64) pl[t] = __expf(sc[(size_t)(mc * 64 + t) * BSZ + b] - M) / S;
    __syncthreads();
    int dl = t & 63, mg = t >> 6;
    int mbase = mc * 64 + mg * 16;
    float4 acc = make_float4(0.f, 0.f, 0.f, 0.f);
    int4 st = *(const int4*)&story[(size_t)(mbase * BSZ + b) * 4];
    float pw = pl[mg * 16];
#pragma unroll 4
    for (int i = 0; i < 16; ++i) {
        int4 s_ = st; float p_ = pw;
        if (i < 15) {
            st = *(const int4*)&story[(size_t)((mbase + i + 1) * BSZ + b) * 4];
            pw = pl[mg * 16 + i + 1];
        }
        float4 a0 = ((const float4*)(Ct + (size_t)s_.x * DSZ))[dl];
        float4 a1 = ((const float4*)(Ct + (size_t)s_.y * DSZ))[dl];
        float4 a2 = ((const float4*)(Ct + (size_t)s_.z * DSZ))[dl];
        float4 a3 = ((const float4*)(Ct + (size_t)s_.w * DSZ))[dl];
        acc.x += p_ * (a0.x + a1.x + a2.x + a3.x);
        acc.y += p_ * (a0.y + a1.y + a2.y + a3.y);
        acc.z += p_ * (a0.z + a1.z + a2.z + a3.z);
        acc.w += p_ * (a0.w + a1.w + a2.w + a3.w);
    }
    pt[mg][dl] = acc;
    __syncthreads();
    if (t < 64) {
        float4 s0 = pt[0][t], s1 = pt[1][t], s2 = pt[2][t], s3 = pt[3][t];
        float* dst = &u[(size_t)b * DSZ + t * 4];
        atomicAdd(dst + 0, s0.x + s1.x + s2.x + s3.x);
        atomicAdd(dst + 1, s0.y + s1.y + s2.y + s3.y);
        atomicAdd(dst + 2, s0.z + s1.z + s2.z + s3.z);
        atomicAdd(dst + 3, s0.w + s1.w + s2.w + s3.w);
    }
}

// ---------------------------------------------------------------------------
// K6: tail0 — pvocab (blocks 0..249, two 256-col passes) || proj h1 (250..499).
__global__ __launch_bounds__(512) void k_tail0(
    const float* __restrict__ C1, const float* __restrict__ u,
    const float* __restrict__ u0, const float* __restrict__ W1w,
    const float* __restrict__ W1b, float* __restrict__ proj,
    float* __restrict__ out_pv)
{
    __shared__ float xS[BSZ * XSTRIDE];
    int gid = blockIdx.x, t = threadIdx.x;
    float acc[8] = {};
    if (gid < 250) {
        int rb = gid * 128;
        // pass 1: u0 against W1w cols 0..255
        stage256(u0, xS, t);
        __syncthreads();
        streamAcc<8>(W1w, 512, xS, acc, rb, rb + 128, t);
        __syncthreads();
        // pass 2: o_k (= u - u0) against W1w cols 256..511
        for (int i = t; i < BSZ * 64; i += 512) {
            int b = i >> 6, c4 = i & 63;
            float4 a = ((const float4*)u)[i];
            float4 c = ((const float4*)u0)[i];
            *(float4*)&xS[(size_t)b * XSTRIDE + c4 * 4] =
                make_float4(a.x - c.x, a.y - c.y, a.z - c.z, a.w - c.w);
        }
        __syncthreads();
        streamAcc<8>(W1w + 256, 512, xS, acc, rb, rb + 128, t);
        writeV<8>(acc, out_pv, W1b, 1, VSZ, rb, rb + 128, t);
    } else {
        stage256(u, xS, t);
        __syncthreads();
        int rb = (gid - 250) * 128;
        streamAcc<8>(C1, DSZ, xS, acc, rb, rb + 128, t);
        writeV<8>(acc, proj, nullptr, 1, VSZ, rb, rb + 128, t);
    }
}

// ---------------------------------------------------------------------------
extern "C" void kernel_launch(void* const* d_in, const int* in_sizes, int n_in,
                              void* d_out, int out_size, void* d_ws, size_t ws_size,
                              hipStream_t stream) {
    const int*   story  = (const int*)d_in[0];
    const int*   encq   = (const int*)d_in[1];
    const float* lasth  = (const float*)d_in[2];
    const float* C      = (const float*)d_in[3];
    const float* postab = (const float*)d_in[4];
    const float* W1w    = (const float*)d_in[5];
    const float* W1b    = (const float*)d_in[6];
    const float* gwih   = (const float*)d_in[7];
    const float* gwhh   = (const float*)d_in[8];
    const float* gbih   = (const float*)d_in[9];
    const float* gbhh   = (const float*)d_in[10];

    float* out = (float*)d_out;
    float* wsf = (float*)d_ws;
    int*   pos  = (int*)d_ws;
    float* u    = wsf + OFF_U;
    float* u0   = wsf + OFF_U0;
    float* pp   = wsf + OFF_PP;
    float* gih  = wsf + OFF_GIH;
    float* sc   = wsf + OFF_SC;
    float* pmax = wsf + OFF_PMAX;
    float* psum = wsf + OFF_PSUM;
    float* proj = wsf + OFF_PROJ;

    k_posgru<<<44, 512, 0, stream>>>(story, encq, lasth, C, gwih, gwhh, pos, gih);
    k_grufin<<<32, 256, 0, stream>>>(gih, gbih, gbhh, lasth, u, u0, out + OUT_HID);
    // proj hop0 (250 blocks x 128 rows) + posproj (9 blocks)
    k_proj<<<259, 512, 0, stream>>>(C, postab, u, proj, pp, 250);

    for (int hop = 0; hop < 3; ++hop) {
        k_scores<<<128, 256, 0, stream>>>(story, pos, proj, pp, sc, pmax, psum,
                                          out, hop);
        if (hop == 2) break;
        k_okpv<<<512, 256, 0, stream>>>(story, sc, pmax, psum,
                                        C + (size_t)(hop + 1) * VD, u);
        if (hop == 0) {
            k_tail0<<<500, 512, 0, stream>>>(C + (size_t)VD, u, u0, W1w, W1b,
                                             proj, out + OUT_PV);
        } else {
            k_proj<<<250, 512, 0, stream>>>(C + (size_t)2 * VD, nullptr, u, proj,
                                            nullptr, 250);
        }
    }
}

// Round 11
// 215.338 us; speedup vs baseline: 4.0050x; 4.0050x over previous
//
#include <hip/hip_runtime.h>

#define VSZ 32000
#define DSZ 256
#define BSZ 32
#define MSZ 1024
#define PSZ 1025
#define VD  (VSZ * DSZ)
#define WTPAD 133     // 133 mod 32 = 5 -> both ds_write (stage) and ds_read (compute) 2-way max

// Workspace layout (float offsets)
#define OFF_U     32768                 // after int pos[M*B]
#define OFF_U0    40960
#define OFF_PP    49152                 // [B][PSZ]
#define OFF_GIH   81952                 // [1536][B]
#define OFF_SC    131104                // [M][B] (idx = m*32+b)
#define OFF_PMAX  163872                // [128][B]
#define OFF_PSUM  167968                // [128][B]
#define OFF_PROJ  172064                // [B][V]

// Output layout (floats): prob_lg [B,M] | p_vocab [B,V] | hidden [1,B,D]
#define OUT_PV  (BSZ * MSZ)
#define OUT_HID (OUT_PV + BSZ * VSZ)

// ---------------------------------------------------------------------------
// One 256-col GEMV pass over 128 rows: acc[k][j] += W[rbeg+vq+64k][:] · x[bg*8+j][:]
// W staged per 32-col tile: coalesced global read (128B segments), transposed
// LDS store. Compute: W-read lanes consecutive (2-way free), x-read uniform
// broadcast. 256 threads = 64 vq x 4 bg.
__device__ __forceinline__ void gemv_pass(
    const float* __restrict__ W, int wstride, int rbeg, int nrows,
    const float* __restrict__ xS, float* __restrict__ Wt,
    float (&acc)[2][8], int t)
{
    const int vq = t & 63, bg = t >> 6;
    const int srow = t >> 3;            // 0..31
    const int scol = (t & 7) * 4;       // 0..28
    for (int kt = 0; kt < 8; ++kt) {
        __syncthreads();                // Wt free (prev compute done)
#pragma unroll
        for (int i = 0; i < 4; ++i) {
            int r = i * 32 + srow;
            float4 wv = make_float4(0.f, 0.f, 0.f, 0.f);
            if (r < nrows)
                wv = *(const float4*)&W[(size_t)(rbeg + r) * wstride + kt * 32 + scol];
            Wt[(scol + 0) * WTPAD + r] = wv.x;
            Wt[(scol + 1) * WTPAD + r] = wv.y;
            Wt[(scol + 2) * WTPAD + r] = wv.z;
            Wt[(scol + 3) * WTPAD + r] = wv.w;
        }
        __syncthreads();                // Wt ready
#pragma unroll
        for (int cw = 0; cw < 8; ++cw) {
            float4 xv[8];
#pragma unroll
            for (int j = 0; j < 8; ++j)
                xv[j] = *(const float4*)&xS[(size_t)(bg * 8 + j) * 256 + kt * 32 + cw * 4];
#pragma unroll
            for (int cc = 0; cc < 4; ++cc) {
                float w0 = Wt[(cw * 4 + cc) * WTPAD + vq];
                float w1 = Wt[(cw * 4 + cc) * WTPAD + vq + 64];
#pragma unroll
                for (int j = 0; j < 8; ++j) {
                    float xj = (cc == 0) ? xv[j].x : (cc == 1) ? xv[j].y
                             : (cc == 2) ? xv[j].z : xv[j].w;
                    acc[0][j] = fmaf(w0, xj, acc[0][j]);
                    acc[1][j] = fmaf(w1, xj, acc[1][j]);
                }
            }
        }
    }
}

__device__ __forceinline__ void gemv_store(
    const float (&acc)[2][8], float* __restrict__ dest,
    const float* __restrict__ bias, size_t drow, size_t dcol,
    int rbeg, int nrows, int t)
{
    const int vq = t & 63, bg = t >> 6;
#pragma unroll
    for (int k = 0; k < 2; ++k) {
        int r = vq + k * 64;
        if (r < nrows) {
            float bv = bias ? bias[rbeg + r] : 0.f;
#pragma unroll
            for (int j = 0; j < 8; ++j)
                dest[(size_t)(rbeg + r) * drow + (size_t)(bg * 8 + j) * dcol] = acc[k][j] + bv;
        }
    }
}

// stage contiguous [32][256] f32 source into xS (flat, no pad: reads are uniform)
__device__ __forceinline__ void stage_x(const float* __restrict__ src,
                                        float* __restrict__ xS, int t) {
    for (int i = t; i < BSZ * 64; i += 256)
        *(float4*)&xS[(size_t)i * 4] = ((const float4*)src)[i];
}

// ---------------------------------------------------------------------------
// K1: positions (blocks 0..31) || GRU matvec (blocks 32..43, 128 rows each)
__global__ __launch_bounds__(256) void k_posgru(
    const int* __restrict__ story, const int* __restrict__ encq,
    const float* __restrict__ lasth, const float* __restrict__ C0,
    const float* __restrict__ gwih, const float* __restrict__ gwhh,
    int* __restrict__ pos, float* __restrict__ gih)
{
    __shared__ float xS[BSZ * 256];
    __shared__ float Wt[32 * WTPAD];
    int gid = blockIdx.x, t = threadIdx.x;
    int lane = t & 63, wid = t >> 6;
    if (gid < 32) {
        int* wtot = (int*)Wt;
        int b = gid, m0 = t * 4;
        int f0 = story[(size_t)((m0 + 0) * BSZ + b) * 4] != 0;
        int f1 = story[(size_t)((m0 + 1) * BSZ + b) * 4] != 0;
        int f2 = story[(size_t)((m0 + 2) * BSZ + b) * 4] != 0;
        int f3 = story[(size_t)((m0 + 3) * BSZ + b) * 4] != 0;
        int p1 = f0 + f1, p2 = p1 + f2, p3 = p2 + f3;
        int x = p3;
        for (int o = 1; o < 64; o <<= 1) {
            int v = __shfl_up(x, o, 64);
            if (lane >= o) x += v;
        }
        if (lane == 63) wtot[wid] = x;
        __syncthreads();
        int wo = 0;
        for (int i = 0; i < wid; ++i) wo += wtot[i];
        int base = wo + x - p3;
        pos[(m0 + 0) * BSZ + b] = f0 ? base + f0 : 0;
        pos[(m0 + 1) * BSZ + b] = f1 ? base + p1 : 0;
        pos[(m0 + 2) * BSZ + b] = f2 ? base + p2 : 0;
        pos[(m0 + 3) * BSZ + b] = f3 ? base + p3 : 0;
    } else {
        int k = gid - 32;               // 0..11
        bool isX = (k < 6);
        for (int i = t; i < BSZ * 64; i += 256) {
            int b = i >> 6, c4 = i & 63;
            float4 v = isX ? ((const float4*)(C0 + (size_t)encq[b] * DSZ))[c4]
                           : ((const float4*)(lasth + (size_t)b * DSZ))[c4];
            *(float4*)&xS[(size_t)(b << 8) + c4 * 4] = v;
        }
        int kr = isX ? k : k - 6;
        const float* W = isX ? gwih : gwhh;
        float* dest = gih + (isX ? 0 : 768 * BSZ);
        float acc[2][8] = {};
        gemv_pass(W, DSZ, kr * 128, 128, xS, Wt, acc, t);
        gemv_store(acc, dest, nullptr, BSZ, 1, kr * 128, 128, t);
    }
}

// ---------------------------------------------------------------------------
// K2: GRU finalize. 32 x 256, idx = b + 32*d (coalesced gih reads).
__global__ void k_grufin(const float* __restrict__ gih,
                         const float* __restrict__ gbih, const float* __restrict__ gbhh,
                         const float* __restrict__ lasth,
                         float* __restrict__ u, float* __restrict__ u0,
                         float* __restrict__ hid)
{
    int idx = blockIdx.x * 256 + threadIdx.x;
    int b = idx & 31, d = idx >> 5;
    float gi0 = gih[(size_t)(0 * DSZ + d) * BSZ + b] + gbih[0 * DSZ + d];
    float gi1 = gih[(size_t)(1 * DSZ + d) * BSZ + b] + gbih[1 * DSZ + d];
    float gi2 = gih[(size_t)(2 * DSZ + d) * BSZ + b] + gbih[2 * DSZ + d];
    float gh0 = gih[(size_t)(3 * DSZ + d) * BSZ + b] + gbhh[0 * DSZ + d];
    float gh1 = gih[(size_t)(4 * DSZ + d) * BSZ + b] + gbhh[1 * DSZ + d];
    float gh2 = gih[(size_t)(5 * DSZ + d) * BSZ + b] + gbhh[2 * DSZ + d];
    float r = 1.f / (1.f + __expf(-(gi0 + gh0)));
    float z = 1.f / (1.f + __expf(-(gi1 + gh1)));
    float n = tanhf(gi2 + r * gh2);
    float h = lasth[(size_t)b * DSZ + d];
    float hn = (1.f - z) * n + z * h;
    int o = b * DSZ + d;
    u[o] = hn; u0[o] = hn; hid[o] = hn;
}

// ---------------------------------------------------------------------------
// K3/K7: proj (blocks < nproj: 128 C-rows each) + posproj tail blocks.
__global__ __launch_bounds__(256) void k_proj(
    const float* __restrict__ Ct, const float* __restrict__ postab,
    const float* __restrict__ u, float* __restrict__ proj,
    float* __restrict__ pp, int nproj)
{
    __shared__ float xS[BSZ * 256];
    __shared__ float Wt[32 * WTPAD];
    int gid = blockIdx.x, t = threadIdx.x;
    stage_x(u, xS, t);
    float acc[2][8] = {};
    if (gid < nproj) {
        int rb = gid * 128;
        gemv_pass(Ct, DSZ, rb, 128, xS, Wt, acc, t);
        gemv_store(acc, proj, nullptr, 1, VSZ, rb, 128, t);
    } else {
        int rb = (gid - nproj) * 128;
        int nr = min(128, PSZ - rb);
        gemv_pass(postab, DSZ, rb, nr, xS, Wt, acc, t);
        gemv_store(acc, pp, nullptr, 1, PSZ, rb, nr, t);
    }
}

// ---------------------------------------------------------------------------
// K4: scores (+ per-block softmax stats for hop<2; logits to out at hop 2).
__global__ void k_scores(const int* __restrict__ story, const int* __restrict__ pos,
                         const float* __restrict__ proj, const float* __restrict__ pp,
                         float* __restrict__ sc, float* __restrict__ pmax,
                         float* __restrict__ psum, float* __restrict__ outlg, int hop)
{
    __shared__ float red[256];
    int gid = blockIdx.x, t = threadIdx.x;
    int idx = gid * 256 + t;
    int b = idx & 31, m = idx >> 5;
    int4 st = *(const int4*)&story[(size_t)idx * 4];
    const float* pb = proj + (size_t)b * VSZ;
    float s = pb[st.x] + pb[st.y] + pb[st.z] + pb[st.w];
    if (hop == 0) s += pp[(size_t)b * PSZ + pos[idx]];
    if (hop == 2) { outlg[b * MSZ + m] = s; return; }
    sc[idx] = s;
    red[t] = s;
    __syncthreads();
    if (t < 32) {
        float mx = red[t];
#pragma unroll
        for (int k = 1; k < 8; ++k) mx = fmaxf(mx, red[k * 32 + t]);
        float sm = 0.f;
#pragma unroll
        for (int k = 0; k < 8; ++k) sm += __expf(red[k * 32 + t] - mx);
        pmax[gid * 32 + t] = mx;
        psum[gid * 32 + t] = sm;
    }
}

// ---------------------------------------------------------------------------
// K5: gather-PV. 512 blocks = (16 mc x 32 b), 256 thr = 4 m-groups x 64 d-lanes.
__global__ __launch_bounds__(256) void k_okpv(
    const int* __restrict__ story, const float* __restrict__ sc,
    const float* __restrict__ pmax, const float* __restrict__ psum,
    const float* __restrict__ Ct, float* __restrict__ u)
{
    int b = blockIdx.x & 31, mc = blockIdx.x >> 5;
    int t = threadIdx.x;
    __shared__ float red[256];
    __shared__ float pl[64];
    __shared__ float4 pt[4][64];
    red[t] = (t < 128) ? pmax[t * 32 + b] : -3.4e38f;
    __syncthreads();
    for (int o = 128; o >= 1; o >>= 1) {
        if (t < o) red[t] = fmaxf(red[t], red[t + o]);
        __syncthreads();
    }
    float M = red[0];
    __syncthreads();
    red[t] = (t < 128) ? psum[t * 32 + b] * __expf(pmax[t * 32 + b] - M) : 0.f;
    __syncthreads();
    for (int o = 128; o >= 1; o >>= 1) {
        if (t < o) red[t] += red[t + o];
        __syncthreads();
    }
    float S = red[0];
    __syncthreads();
    if (t < 64) pl[t] = __expf(sc[(size_t)(mc * 64 + t) * BSZ + b] - M) / S;
    __syncthreads();
    int dl = t & 63, mg = t >> 6;
    int mbase = mc * 64 + mg * 16;
    float4 acc = make_float4(0.f, 0.f, 0.f, 0.f);
    int4 st = *(const int4*)&story[(size_t)(mbase * BSZ + b) * 4];
    float pw = pl[mg * 16];
#pragma unroll 4
    for (int i = 0; i < 16; ++i) {
        int4 s_ = st; float p_ = pw;
        if (i < 15) {
            st = *(const int4*)&story[(size_t)((mbase + i + 1) * BSZ + b) * 4];
            pw = pl[mg * 16 + i + 1];
        }
        float4 a0 = ((const float4*)(Ct + (size_t)s_.x * DSZ))[dl];
        float4 a1 = ((const float4*)(Ct + (size_t)s_.y * DSZ))[dl];
        float4 a2 = ((const float4*)(Ct + (size_t)s_.z * DSZ))[dl];
        float4 a3 = ((const float4*)(Ct + (size_t)s_.w * DSZ))[dl];
        acc.x += p_ * (a0.x + a1.x + a2.x + a3.x);
        acc.y += p_ * (a0.y + a1.y + a2.y + a3.y);
        acc.z += p_ * (a0.z + a1.z + a2.z + a3.z);
        acc.w += p_ * (a0.w + a1.w + a2.w + a3.w);
    }
    pt[mg][dl] = acc;
    __syncthreads();
    if (t < 64) {
        float4 s0 = pt[0][t], s1 = pt[1][t], s2 = pt[2][t], s3 = pt[3][t];
        float* dst = &u[(size_t)b * DSZ + t * 4];
        atomicAdd(dst + 0, s0.x + s1.x + s2.x + s3.x);
        atomicAdd(dst + 1, s0.y + s1.y + s2.y + s3.y);
        atomicAdd(dst + 2, s0.z + s1.z + s2.z + s3.z);
        atomicAdd(dst + 3, s0.w + s1.w + s2.w + s3.w);
    }
}

// ---------------------------------------------------------------------------
// K6: tail0 — pvocab (blocks 0..249, 2 K-passes) || proj h1 (250..499).
__global__ __launch_bounds__(256) void k_tail0(
    const float* __restrict__ C1, const float* __restrict__ u,
    const float* __restrict__ u0, const float* __restrict__ W1w,
    const float* __restrict__ W1b, float* __restrict__ proj,
    float* __restrict__ out_pv)
{
    __shared__ float xS[BSZ * 256];
    __shared__ float Wt[32 * WTPAD];
    int gid = blockIdx.x, t = threadIdx.x;
    float acc[2][8] = {};
    if (gid < 250) {
        int rb = gid * 128;
        stage_x(u0, xS, t);                       // pass 1: u0 vs cols 0..255
        gemv_pass(W1w, 512, rb, 128, xS, Wt, acc, t);
        __syncthreads();                          // pass-1 compute done
        for (int i = t; i < BSZ * 64; i += 256) { // pass 2 x: o_k = u - u0
            float4 a = ((const float4*)u)[i];
            float4 c = ((const float4*)u0)[i];
            *(float4*)&xS[(size_t)i * 4] =
                make_float4(a.x - c.x, a.y - c.y, a.z - c.z, a.w - c.w);
        }
        gemv_pass(W1w + 256, 512, rb, 128, xS, Wt, acc, t);
        gemv_store(acc, out_pv, W1b, 1, VSZ, rb, 128, t);
    } else {
        stage_x(u, xS, t);
        int rb = (gid - 250) * 128;
        gemv_pass(C1, DSZ, rb, 128, xS, Wt, acc, t);
        gemv_store(acc, proj, nullptr, 1, VSZ, rb, 128, t);
    }
}

// ---------------------------------------------------------------------------
extern "C" void kernel_launch(void* const* d_in, const int* in_sizes, int n_in,
                              void* d_out, int out_size, void* d_ws, size_t ws_size,
                              hipStream_t stream) {
    const int*   story  = (const int*)d_in[0];
    const int*   encq   = (const int*)d_in[1];
    const float* lasth  = (const float*)d_in[2];
    const float* C      = (const float*)d_in[3];
    const float* postab = (const float*)d_in[4];
    const float* W1w    = (const float*)d_in[5];
    const float* W1b    = (const float*)d_in[6];
    const float* gwih   = (const float*)d_in[7];
    const float* gwhh   = (const float*)d_in[8];
    const float* gbih   = (const float*)d_in[9];
    const float* gbhh   = (const float*)d_in[10];

    float* out = (float*)d_out;
    float* wsf = (float*)d_ws;
    int*   pos  = (int*)d_ws;
    float* u    = wsf + OFF_U;
    float* u0   = wsf + OFF_U0;
    float* pp   = wsf + OFF_PP;
    float* gih  = wsf + OFF_GIH;
    float* sc   = wsf + OFF_SC;
    float* pmax = wsf + OFF_PMAX;
    float* psum = wsf + OFF_PSUM;
    float* proj = wsf + OFF_PROJ;

    k_posgru<<<44, 256, 0, stream>>>(story, encq, lasth, C, gwih, gwhh, pos, gih);
    k_grufin<<<32, 256, 0, stream>>>(gih, gbih, gbhh, lasth, u, u0, out + OUT_HID);
    // proj hop0 (250 blocks x 128 rows) + posproj (9 blocks)
    k_proj<<<259, 256, 0, stream>>>(C, postab, u, proj, pp, 250);

    for (int hop = 0; hop < 3; ++hop) {
        k_scores<<<128, 256, 0, stream>>>(story, pos, proj, pp, sc, pmax, psum,
                                          out, hop);
        if (hop == 2) break;
        k_okpv<<<512, 256, 0, stream>>>(story, sc, pmax, psum,
                                        C + (size_t)(hop + 1) * VD, u);
        if (hop == 0) {
            k_tail0<<<500, 256, 0, stream>>>(C + (size_t)VD, u, u0, W1w, W1b,
                                             proj, out + OUT_PV);
        } else {
            k_proj<<<250, 256, 0, stream>>>(C + (size_t)2 * VD, nullptr, u, proj,
                                            nullptr, 250);
        }
    }
}

// Round 12
// 184.134 us; speedup vs baseline: 4.6838x; 1.1695x over previous
//
#include <hip/hip_runtime.h>

#define VSZ 32000
#define DSZ 256
#define BSZ 32
#define MSZ 1024
#define PSZ 1025
#define VD  (VSZ * DSZ)
#define WTPAD 133     // 133 mod 32 = 5 -> both ds_write (stage) and ds_read (compute) 2-way max

// Workspace layout (float offsets)
#define OFF_U     32768                 // after int pos[M*B]
#define OFF_U0    40960
#define OFF_PP    49152                 // [B][PSZ]
#define OFF_GIH   81952                 // [1536][B]
#define OFF_SC    131104                // [M][B] (idx = m*32+b)
#define OFF_PMAX  163872                // [128][B]
#define OFF_PSUM  167968                // [128][B]
#define OFF_PROJ  172064                // [B][V]

// Output layout (floats): prob_lg [B,M] | p_vocab [B,V] | hidden [1,B,D]
#define OUT_PV  (BSZ * MSZ)
#define OUT_HID (OUT_PV + BSZ * VSZ)

// ---------------------------------------------------------------------------
// One 256-col GEMV pass over 128 rows with REGISTER-DOUBLE-BUFFERED staging:
// tile k+1's global loads are issued right after tile k's "ready" barrier and
// fly during tile k's compute (the vmcnt wait lands at the next LDS write).
// W staged transposed (coalesced global read, conflict-free scalar writes);
// compute: W-reads consecutive-lane b32 (conflict-free), x-reads uniform bcast.
__device__ __forceinline__ void gemv_pass(
    const float* __restrict__ W, int wstride, int rbeg, int nrows,
    const float* __restrict__ xS, float* __restrict__ Wt,
    float (&acc)[2][8], int t)
{
    const int vq = t & 63, bg = t >> 6;
    const int srow = t >> 3;            // 0..31
    const int scol = (t & 7) * 4;       // 0..28
    float4 wreg[4];
#pragma unroll
    for (int i = 0; i < 4; ++i) {
        int r = i * 32 + srow;
        wreg[i] = (r < nrows)
            ? *(const float4*)&W[(size_t)(rbeg + r) * wstride + scol]
            : make_float4(0.f, 0.f, 0.f, 0.f);
    }
    for (int kt = 0; kt < 8; ++kt) {
        __syncthreads();                // Wt free (prev compute done)
#pragma unroll
        for (int i = 0; i < 4; ++i) {   // waits vmcnt for wreg here
            int r = i * 32 + srow;
            Wt[(scol + 0) * WTPAD + r] = wreg[i].x;
            Wt[(scol + 1) * WTPAD + r] = wreg[i].y;
            Wt[(scol + 2) * WTPAD + r] = wreg[i].z;
            Wt[(scol + 3) * WTPAD + r] = wreg[i].w;
        }
        __syncthreads();                // Wt ready
        if (kt < 7) {                   // prefetch tile kt+1 during compute
#pragma unroll
            for (int i = 0; i < 4; ++i) {
                int r = i * 32 + srow;
                wreg[i] = (r < nrows)
                    ? *(const float4*)&W[(size_t)(rbeg + r) * wstride + (kt + 1) * 32 + scol]
                    : make_float4(0.f, 0.f, 0.f, 0.f);
            }
        }
#pragma unroll
        for (int cw = 0; cw < 8; ++cw) {
            float4 xv[8];
#pragma unroll
            for (int j = 0; j < 8; ++j)
                xv[j] = *(const float4*)&xS[(size_t)(bg * 8 + j) * 256 + kt * 32 + cw * 4];
#pragma unroll
            for (int cc = 0; cc < 4; ++cc) {
                float w0 = Wt[(cw * 4 + cc) * WTPAD + vq];
                float w1 = Wt[(cw * 4 + cc) * WTPAD + vq + 64];
#pragma unroll
                for (int j = 0; j < 8; ++j) {
                    float xj = (cc == 0) ? xv[j].x : (cc == 1) ? xv[j].y
                             : (cc == 2) ? xv[j].z : xv[j].w;
                    acc[0][j] = fmaf(w0, xj, acc[0][j]);
                    acc[1][j] = fmaf(w1, xj, acc[1][j]);
                }
            }
        }
    }
}

__device__ __forceinline__ void gemv_store(
    const float (&acc)[2][8], float* __restrict__ dest,
    const float* __restrict__ bias, size_t drow, size_t dcol,
    int rbeg, int nrows, int t)
{
    const int vq = t & 63, bg = t >> 6;
#pragma unroll
    for (int k = 0; k < 2; ++k) {
        int r = vq + k * 64;
        if (r < nrows) {
            float bv = bias ? bias[rbeg + r] : 0.f;
#pragma unroll
            for (int j = 0; j < 8; ++j)
                dest[(size_t)(rbeg + r) * drow + (size_t)(bg * 8 + j) * dcol] = acc[k][j] + bv;
        }
    }
}

// stage contiguous [32][256] f32 source into xS (flat: compute reads are uniform)
__device__ __forceinline__ void stage_x(const float* __restrict__ src,
                                        float* __restrict__ xS, int t) {
    for (int i = t; i < BSZ * 64; i += 256)
        *(float4*)&xS[(size_t)i * 4] = ((const float4*)src)[i];
}

// ---------------------------------------------------------------------------
// K1: positions (blocks 0..31) || GRU matvec (blocks 32..43, 128 rows each)
__global__ __launch_bounds__(256) void k_posgru(
    const int* __restrict__ story, const int* __restrict__ encq,
    const float* __restrict__ lasth, const float* __restrict__ C0,
    const float* __restrict__ gwih, const float* __restrict__ gwhh,
    int* __restrict__ pos, float* __restrict__ gih)
{
    __shared__ float xS[BSZ * 256];
    __shared__ float Wt[32 * WTPAD];
    int gid = blockIdx.x, t = threadIdx.x;
    int lane = t & 63, wid = t >> 6;
    if (gid < 32) {
        int* wtot = (int*)Wt;
        int b = gid, m0 = t * 4;
        int f0 = story[(size_t)((m0 + 0) * BSZ + b) * 4] != 0;
        int f1 = story[(size_t)((m0 + 1) * BSZ + b) * 4] != 0;
        int f2 = story[(size_t)((m0 + 2) * BSZ + b) * 4] != 0;
        int f3 = story[(size_t)((m0 + 3) * BSZ + b) * 4] != 0;
        int p1 = f0 + f1, p2 = p1 + f2, p3 = p2 + f3;
        int x = p3;
        for (int o = 1; o < 64; o <<= 1) {
            int v = __shfl_up(x, o, 64);
            if (lane >= o) x += v;
        }
        if (lane == 63) wtot[wid] = x;
        __syncthreads();
        int wo = 0;
        for (int i = 0; i < wid; ++i) wo += wtot[i];
        int base = wo + x - p3;
        pos[(m0 + 0) * BSZ + b] = f0 ? base + f0 : 0;
        pos[(m0 + 1) * BSZ + b] = f1 ? base + p1 : 0;
        pos[(m0 + 2) * BSZ + b] = f2 ? base + p2 : 0;
        pos[(m0 + 3) * BSZ + b] = f3 ? base + p3 : 0;
    } else {
        int k = gid - 32;               // 0..11
        bool isX = (k < 6);
        for (int i = t; i < BSZ * 64; i += 256) {
            int b = i >> 6, c4 = i & 63;
            float4 v = isX ? ((const float4*)(C0 + (size_t)encq[b] * DSZ))[c4]
                           : ((const float4*)(lasth + (size_t)b * DSZ))[c4];
            *(float4*)&xS[(size_t)(b << 8) + c4 * 4] = v;
        }
        int kr = isX ? k : k - 6;
        const float* W = isX ? gwih : gwhh;
        float* dest = gih + (isX ? 0 : 768 * BSZ);
        float acc[2][8] = {};
        gemv_pass(W, DSZ, kr * 128, 128, xS, Wt, acc, t);
        gemv_store(acc, dest, nullptr, BSZ, 1, kr * 128, 128, t);
    }
}

// ---------------------------------------------------------------------------
// K2: GRU finalize. 32 x 256, idx = b + 32*d (coalesced gih reads).
__global__ void k_grufin(const float* __restrict__ gih,
                         const float* __restrict__ gbih, const float* __restrict__ gbhh,
                         const float* __restrict__ lasth,
                         float* __restrict__ u, float* __restrict__ u0,
                         float* __restrict__ hid)
{
    int idx = blockIdx.x * 256 + threadIdx.x;
    int b = idx & 31, d = idx >> 5;
    float gi0 = gih[(size_t)(0 * DSZ + d) * BSZ + b] + gbih[0 * DSZ + d];
    float gi1 = gih[(size_t)(1 * DSZ + d) * BSZ + b] + gbih[1 * DSZ + d];
    float gi2 = gih[(size_t)(2 * DSZ + d) * BSZ + b] + gbih[2 * DSZ + d];
    float gh0 = gih[(size_t)(3 * DSZ + d) * BSZ + b] + gbhh[0 * DSZ + d];
    float gh1 = gih[(size_t)(4 * DSZ + d) * BSZ + b] + gbhh[1 * DSZ + d];
    float gh2 = gih[(size_t)(5 * DSZ + d) * BSZ + b] + gbhh[2 * DSZ + d];
    float r = 1.f / (1.f + __expf(-(gi0 + gh0)));
    float z = 1.f / (1.f + __expf(-(gi1 + gh1)));
    float n = tanhf(gi2 + r * gh2);
    float h = lasth[(size_t)b * DSZ + d];
    float hn = (1.f - z) * n + z * h;
    int o = b * DSZ + d;
    u[o] = hn; u0[o] = hn; hid[o] = hn;
}

// ---------------------------------------------------------------------------
// K3/K7: proj (blocks < nproj: 128 C-rows each) + posproj tail blocks.
__global__ __launch_bounds__(256) void k_proj(
    const float* __restrict__ Ct, const float* __restrict__ postab,
    const float* __restrict__ u, float* __restrict__ proj,
    float* __restrict__ pp, int nproj)
{
    __shared__ float xS[BSZ * 256];
    __shared__ float Wt[32 * WTPAD];
    int gid = blockIdx.x, t = threadIdx.x;
    stage_x(u, xS, t);
    float acc[2][8] = {};
    if (gid < nproj) {
        int rb = gid * 128;
        gemv_pass(Ct, DSZ, rb, 128, xS, Wt, acc, t);
        gemv_store(acc, proj, nullptr, 1, VSZ, rb, 128, t);
    } else {
        int rb = (gid - nproj) * 128;
        int nr = min(128, PSZ - rb);
        gemv_pass(postab, DSZ, rb, nr, xS, Wt, acc, t);
        gemv_store(acc, pp, nullptr, 1, PSZ, rb, nr, t);
    }
}

// ---------------------------------------------------------------------------
// K4: scores (+ per-block softmax stats for hop<2; logits to out at hop 2).
__global__ void k_scores(const int* __restrict__ story, const int* __restrict__ pos,
                         const float* __restrict__ proj, const float* __restrict__ pp,
                         float* __restrict__ sc, float* __restrict__ pmax,
                         float* __restrict__ psum, float* __restrict__ outlg, int hop)
{
    __shared__ float red[256];
    int gid = blockIdx.x, t = threadIdx.x;
    int idx = gid * 256 + t;
    int b = idx & 31, m = idx >> 5;
    int4 st = *(const int4*)&story[(size_t)idx * 4];
    const float* pb = proj + (size_t)b * VSZ;
    float s = pb[st.x] + pb[st.y] + pb[st.z] + pb[st.w];
    if (hop == 0) s += pp[(size_t)b * PSZ + pos[idx]];
    if (hop == 2) { outlg[b * MSZ + m] = s; return; }
    sc[idx] = s;
    red[t] = s;
    __syncthreads();
    if (t < 32) {
        float mx = red[t];
#pragma unroll
        for (int k = 1; k < 8; ++k) mx = fmaxf(mx, red[k * 32 + t]);
        float sm = 0.f;
#pragma unroll
        for (int k = 0; k < 8; ++k) sm += __expf(red[k * 32 + t] - mx);
        pmax[gid * 32 + t] = mx;
        psum[gid * 32 + t] = sm;
    }
}

// ---------------------------------------------------------------------------
// K5: gather-PV. 512 blocks = (16 mc x 32 b), 256 thr = 4 m-groups x 64 d-lanes.
__global__ __launch_bounds__(256) void k_okpv(
    const int* __restrict__ story, const float* __restrict__ sc,
    const float* __restrict__ pmax, const float* __restrict__ psum,
    const float* __restrict__ Ct, float* __restrict__ u)
{
    int b = blockIdx.x & 31, mc = blockIdx.x >> 5;
    int t = threadIdx.x;
    __shared__ float red[256];
    __shared__ float pl[64];
    __shared__ float4 pt[4][64];
    red[t] = (t < 128) ? pmax[t * 32 + b] : -3.4e38f;
    __syncthreads();
    for (int o = 128; o >= 1; o >>= 1) {
        if (t < o) red[t] = fmaxf(red[t], red[t + o]);
        __syncthreads();
    }
    float M = red[0];
    __syncthreads();
    red[t] = (t < 128) ? psum[t * 32 + b] * __expf(pmax[t * 32 + b] - M) : 0.f;
    __syncthreads();
    for (int o = 128; o >= 1; o >>= 1) {
        if (t < o) red[t] += red[t + o];
        __syncthreads();
    }
    float S = red[0];
    __syncthreads();
    if (t < 64) pl[t] = __expf(sc[(size_t)(mc * 64 + t) * BSZ + b] - M) / S;
    __syncthreads();
    int dl = t & 63, mg = t >> 6;
    int mbase = mc * 64 + mg * 16;
    float4 acc = make_float4(0.f, 0.f, 0.f, 0.f);
    int4 st = *(const int4*)&story[(size_t)(mbase * BSZ + b) * 4];
    float pw = pl[mg * 16];
#pragma unroll 4
    for (int i = 0; i < 16; ++i) {
        int4 s_ = st; float p_ = pw;
        if (i < 15) {
            st = *(const int4*)&story[(size_t)((mbase + i + 1) * BSZ + b) * 4];
            pw = pl[mg * 16 + i + 1];
        }
        float4 a0 = ((const float4*)(Ct + (size_t)s_.x * DSZ))[dl];
        float4 a1 = ((const float4*)(Ct + (size_t)s_.y * DSZ))[dl];
        float4 a2 = ((const float4*)(Ct + (size_t)s_.z * DSZ))[dl];
        float4 a3 = ((const float4*)(Ct + (size_t)s_.w * DSZ))[dl];
        acc.x += p_ * (a0.x + a1.x + a2.x + a3.x);
        acc.y += p_ * (a0.y + a1.y + a2.y + a3.y);
        acc.z += p_ * (a0.z + a1.z + a2.z + a3.z);
        acc.w += p_ * (a0.w + a1.w + a2.w + a3.w);
    }
    pt[mg][dl] = acc;
    __syncthreads();
    if (t < 64) {
        float4 s0 = pt[0][t], s1 = pt[1][t], s2 = pt[2][t], s3 = pt[3][t];
        float* dst = &u[(size_t)b * DSZ + t * 4];
        atomicAdd(dst + 0, s0.x + s1.x + s2.x + s3.x);
        atomicAdd(dst + 1, s0.y + s1.y + s2.y + s3.y);
        atomicAdd(dst + 2, s0.z + s1.z + s2.z + s3.z);
        atomicAdd(dst + 3, s0.w + s1.w + s2.w + s3.w);
    }
}

// ---------------------------------------------------------------------------
// K6: tail0 — pvocab (blocks 0..249, 2 K-passes) || proj h1 (250..499).
__global__ __launch_bounds__(256) void k_tail0(
    const float* __restrict__ C1, const float* __restrict__ u,
    const float* __restrict__ u0, const float* __restrict__ W1w,
    const float* __restrict__ W1b, float* __restrict__ proj,
    float* __restrict__ out_pv)
{
    __shared__ float xS[BSZ * 256];
    __shared__ float Wt[32 * WTPAD];
    int gid = blockIdx.x, t = threadIdx.x;
    float acc[2][8] = {};
    if (gid < 250) {
        int rb = gid * 128;
        stage_x(u0, xS, t);                       // pass 1: u0 vs cols 0..255
        gemv_pass(W1w, 512, rb, 128, xS, Wt, acc, t);
        __syncthreads();                          // pass-1 compute done
        for (int i = t; i < BSZ * 64; i += 256) { // pass 2 x: o_k = u - u0
            float4 a = ((const float4*)u)[i];
            float4 c = ((const float4*)u0)[i];
            *(float4*)&xS[(size_t)i * 4] =
                make_float4(a.x - c.x, a.y - c.y, a.z - c.z, a.w - c.w);
        }
        gemv_pass(W1w + 256, 512, rb, 128, xS, Wt, acc, t);
        gemv_store(acc, out_pv, W1b, 1, VSZ, rb, 128, t);
    } else {
        stage_x(u, xS, t);
        int rb = (gid - 250) * 128;
        gemv_pass(C1, DSZ, rb, 128, xS, Wt, acc, t);
        gemv_store(acc, proj, nullptr, 1, VSZ, rb, 128, t);
    }
}

// ---------------------------------------------------------------------------
extern "C" void kernel_launch(void* const* d_in, const int* in_sizes, int n_in,
                              void* d_out, int out_size, void* d_ws, size_t ws_size,
                              hipStream_t stream) {
    const int*   story  = (const int*)d_in[0];
    const int*   encq   = (const int*)d_in[1];
    const float* lasth  = (const float*)d_in[2];
    const float* C      = (const float*)d_in[3];
    const float* postab = (const float*)d_in[4];
    const float* W1w    = (const float*)d_in[5];
    const float* W1b    = (const float*)d_in[6];
    const float* gwih   = (const float*)d_in[7];
    const float* gwhh   = (const float*)d_in[8];
    const float* gbih   = (const float*)d_in[9];
    const float* gbhh   = (const float*)d_in[10];

    float* out = (float*)d_out;
    float* wsf = (float*)d_ws;
    int*   pos  = (int*)d_ws;
    float* u    = wsf + OFF_U;
    float* u0   = wsf + OFF_U0;
    float* pp   = wsf + OFF_PP;
    float* gih  = wsf + OFF_GIH;
    float* sc   = wsf + OFF_SC;
    float* pmax = wsf + OFF_PMAX;
    float* psum = wsf + OFF_PSUM;
    float* proj = wsf + OFF_PROJ;

    k_posgru<<<44, 256, 0, stream>>>(story, encq, lasth, C, gwih, gwhh, pos, gih);
    k_grufin<<<32, 256, 0, stream>>>(gih, gbih, gbhh, lasth, u, u0, out + OUT_HID);
    // proj hop0 (250 blocks x 128 rows) + posproj (9 blocks)
    k_proj<<<259, 256, 0, stream>>>(C, postab, u, proj, pp, 250);

    for (int hop = 0; hop < 3; ++hop) {
        k_scores<<<128, 256, 0, stream>>>(story, pos, proj, pp, sc, pmax, psum,
                                          out, hop);
        if (hop == 2) break;
        k_okpv<<<512, 256, 0, stream>>>(story, sc, pmax, psum,
                                        C + (size_t)(hop + 1) * VD, u);
        if (hop == 0) {
            k_tail0<<<500, 256, 0, stream>>>(C + (size_t)VD, u, u0, W1w, W1b,
                                             proj, out + OUT_PV);
        } else {
            k_proj<<<250, 256, 0, stream>>>(C + (size_t)2 * VD, nullptr, u, proj,
                                            nullptr, 250);
        }
    }
}